// Round 1
// baseline (1002.550 us; speedup 1.0000x reference)
//
#include <hip/hip_runtime.h>

#define FP8_MAX 448.0f

typedef float f32x4 __attribute__((ext_vector_type(4)));

// ---- async global->LDS, 16B per lane (m97: the single biggest win) ----
__device__ __forceinline__ void load_lds16(const void* g, void* l) {
  __builtin_amdgcn_global_load_lds(
      (__attribute__((address_space(1))) void*)g,
      (__attribute__((address_space(3))) void*)l,
      16, 0, 0);
}

// ---- zero the two absmax slots (d_ws is poisoned 0xAA each call) ----
__global__ void init_scales_kernel(unsigned* s) {
  s[0] = 0u;
  s[1] = 0u;
}

// ---- per-tensor absmax: float4 grid-stride + wave64 reduce + atomicMax ----
__global__ void absmax_kernel(const float4* __restrict__ in,
                              unsigned* __restrict__ out, int n4) {
  float m = 0.f;
  int stride = gridDim.x * blockDim.x;
  for (int i = blockIdx.x * blockDim.x + threadIdx.x; i < n4; i += stride) {
    float4 v = in[i];
    m = fmaxf(m, fmaxf(fmaxf(fabsf(v.x), fabsf(v.y)),
                       fmaxf(fabsf(v.z), fabsf(v.w))));
  }
#pragma unroll
  for (int off = 32; off > 0; off >>= 1)
    m = fmaxf(m, __shfl_down(m, off, 64));
  __shared__ float sred[4];
  int lane = threadIdx.x & 63;
  int wid = threadIdx.x >> 6;
  if (lane == 0) sred[wid] = m;
  __syncthreads();
  if (threadIdx.x == 0) {
    m = fmaxf(fmaxf(sred[0], sred[1]), fmaxf(sred[2], sred[3]));
    atomicMax(out, __float_as_uint(m));  // positive floats: uint order == float order
  }
}

// ---- quantize x [M,K] fp32 -> fp8 e4m3 (16 elems/thread, 16B store) ----
__global__ void quant_x_kernel(const float* __restrict__ x,
                               unsigned char* __restrict__ xq,
                               const unsigned* __restrict__ sc, long long n16) {
  long long t = (long long)blockIdx.x * blockDim.x + threadIdx.x;
  if (t >= n16) return;
  float s = FP8_MAX / __uint_as_float(sc[0]);
  const float4* xv = (const float4*)x + t * 4;
  unsigned r[4];
#pragma unroll
  for (int i = 0; i < 4; ++i) {
    float4 v = xv[i];
    float q0 = fminf(fmaxf(v.x * s, -FP8_MAX), FP8_MAX);
    float q1 = fminf(fmaxf(v.y * s, -FP8_MAX), FP8_MAX);
    float q2 = fminf(fmaxf(v.z * s, -FP8_MAX), FP8_MAX);
    float q3 = fminf(fmaxf(v.w * s, -FP8_MAX), FP8_MAX);
    int p = __builtin_amdgcn_cvt_pk_fp8_f32(q0, q1, 0, false);
    p = __builtin_amdgcn_cvt_pk_fp8_f32(q2, q3, p, true);
    r[i] = (unsigned)p;
  }
  uint4 o;
  o.x = r[0]; o.y = r[1]; o.z = r[2]; o.w = r[3];
  *(uint4*)(xq + t * 16) = o;
}

// ---- transpose+quantize w [K,N] fp32 -> wq_t [N,K] fp8, 64x64 LDS tiles ----
__global__ void quant_wt_kernel(const float* __restrict__ w,
                                unsigned char* __restrict__ wq,
                                const unsigned* __restrict__ sc, int K, int N) {
  __shared__ float tile[64][65];  // +1 pad: transposed reads land 2-way max
  float s = FP8_MAX / __uint_as_float(sc[1]);
  int nt = blockIdx.x * 64;
  int kt = blockIdx.y * 64;
#pragma unroll
  for (int it = 0; it < 4; ++it) {
    int idx = threadIdx.x + it * 256;
    int r = idx >> 4;        // k row within tile
    int c = (idx & 15) * 4;  // n col within tile
    float4 v = *(const float4*)&w[(size_t)(kt + r) * N + nt + c];
    tile[r][c + 0] = v.x; tile[r][c + 1] = v.y;
    tile[r][c + 2] = v.z; tile[r][c + 3] = v.w;
  }
  __syncthreads();
  int n = threadIdx.x >> 2;          // 0..63
  int k0 = (threadIdx.x & 3) * 16;   // 0,16,32,48
  unsigned r4[4];
#pragma unroll
  for (int q = 0; q < 4; ++q) {
    float a0 = fminf(fmaxf(tile[k0 + q * 4 + 0][n] * s, -FP8_MAX), FP8_MAX);
    float a1 = fminf(fmaxf(tile[k0 + q * 4 + 1][n] * s, -FP8_MAX), FP8_MAX);
    float a2 = fminf(fmaxf(tile[k0 + q * 4 + 2][n] * s, -FP8_MAX), FP8_MAX);
    float a3 = fminf(fmaxf(tile[k0 + q * 4 + 3][n] * s, -FP8_MAX), FP8_MAX);
    int p = __builtin_amdgcn_cvt_pk_fp8_f32(a0, a1, 0, false);
    p = __builtin_amdgcn_cvt_pk_fp8_f32(a2, a3, p, true);
    r4[q] = (unsigned)p;
  }
  uint4 o;
  o.x = r4[0]; o.y = r4[1]; o.z = r4[2]; o.w = r4[3];
  *(uint4*)&wq[(size_t)(nt + n) * K + kt + k0] = o;
}

// ---- fp8 GEMM: C[M,N] = Aq[M,K] . Bq[N,K]^T, dequant in epilogue ----
// m97/m145 structure: 128x128 tile, BK=64B, 4 waves (2x2) each 64x64,
// mfma_f32_16x16x32_fp8_fp8, global_load_lds 16B staging,
// XOR 16B-chunk swizzle s(row)=(row>>1)&3 so ds_read_b64 frags are
// 2-way-per-bank (free, m136).
__global__ __launch_bounds__(256) void gemm_fp8_kernel(
    const unsigned char* __restrict__ A,   // [M,K] fp8
    const unsigned char* __restrict__ B,   // [N,K] fp8
    float* __restrict__ C,                 // [M,N] fp32
    const unsigned* __restrict__ am, int M, int N, int K) {
  __shared__ unsigned char lA[128 * 64];
  __shared__ unsigned char lB[128 * 64];

  const int tid = threadIdx.x;
  const int lane = tid & 63;
  const int wave = tid >> 6;
  const int wm = (wave >> 1) * 64;
  const int wn = (wave & 1) * 64;
  const int quad = lane >> 4;  // 0..3
  const int l16 = lane & 15;

  const int m0 = blockIdx.y * 128;
  const int n0 = blockIdx.x * 128;

  f32x4 zero4 = {0.f, 0.f, 0.f, 0.f};
  f32x4 acc[4][4];
#pragma unroll
  for (int i = 0; i < 4; ++i)
#pragma unroll
    for (int j = 0; j < 4; ++j) acc[i][j] = zero4;

  // staging: 16B chunk f = tid (+256); row=f>>2, lds chunk c=f&3,
  // source global chunk = c ^ ((row>>1)&3)
  const int row0 = tid >> 2;        // 0..63
  const int c0 = tid & 3;
  const int sc0 = c0 ^ ((row0 >> 1) & 3);
  const int row1 = row0 + 64;       // (row1>>1)&3 == (row0>>1)&3 + 32 -> same &3
  const unsigned char* gA0 = A + (size_t)(m0 + row0) * K + sc0 * 16;
  const unsigned char* gA1 = A + (size_t)(m0 + row1) * K + sc0 * 16;
  const unsigned char* gB0 = B + (size_t)(n0 + row0) * K + sc0 * 16;
  const unsigned char* gB1 = B + (size_t)(n0 + row1) * K + sc0 * 16;
  unsigned char* sA0 = &lA[tid * 16];
  unsigned char* sA1 = &lA[(tid + 256) * 16];
  unsigned char* sB0 = &lB[tid * 16];
  unsigned char* sB1 = &lB[(tid + 256) * 16];

  // LDS fragment read offsets (loop-invariant): kstep s, m-tile i
  int aoff[2][4], boff[2][4];
#pragma unroll
  for (int s = 0; s < 2; ++s)
#pragma unroll
    for (int i = 0; i < 4; ++i) {
      int chunk = s * 2 + (quad >> 1);
      int mrow = wm + i * 16 + l16;
      int nrow = wn + i * 16 + l16;
      aoff[s][i] = mrow * 64 + (chunk ^ ((mrow >> 1) & 3)) * 16 + (quad & 1) * 8;
      boff[s][i] = nrow * 64 + (chunk ^ ((nrow >> 1) & 3)) * 16 + (quad & 1) * 8;
    }

  for (int k0 = 0; k0 < K; k0 += 64) {
    load_lds16(gA0 + k0, sA0);
    load_lds16(gA1 + k0, sA1);
    load_lds16(gB0 + k0, sB0);
    load_lds16(gB1 + k0, sB1);
    __syncthreads();  // drains vmcnt -> tiles resident
#pragma unroll
    for (int s = 0; s < 2; ++s) {
      long long af[4], bf[4];
#pragma unroll
      for (int i = 0; i < 4; ++i) {
        af[i] = *(const long long*)&lA[aoff[s][i]];
        bf[i] = *(const long long*)&lB[boff[s][i]];
      }
#pragma unroll
      for (int i = 0; i < 4; ++i)
#pragma unroll
        for (int j = 0; j < 4; ++j)
          acc[i][j] = __builtin_amdgcn_mfma_f32_16x16x32_fp8_fp8(
              af[i], bf[j], acc[i][j], 0, 0, 0);
    }
    __syncthreads();  // compute done before next staging overwrites LDS
  }

  // dequant: y / (sx*sw), sx=448/ax, sw=448/aw (match reference expressions)
  float ax = __uint_as_float(am[0]);
  float aw = __uint_as_float(am[1]);
  float sx = FP8_MAX / ax;
  float sw = FP8_MAX / aw;
  float inv = 1.f / (sx * sw);

  // C/D layout (dtype-independent, m89/m121-128): col=lane&15, row=quad*4+r
#pragma unroll
  for (int i = 0; i < 4; ++i) {
    int crow = m0 + wm + i * 16 + quad * 4;
#pragma unroll
    for (int j = 0; j < 4; ++j) {
      int ccol = n0 + wn + j * 16 + l16;
#pragma unroll
      for (int r = 0; r < 4; ++r)
        C[(size_t)(crow + r) * N + ccol] = acc[i][j][r] * inv;
    }
  }
}

extern "C" void kernel_launch(void* const* d_in, const int* in_sizes, int n_in,
                              void* d_out, int out_size, void* d_ws,
                              size_t ws_size, hipStream_t stream) {
  const int M = 16384, K = 4096, N = 4096;
  const float* x = (const float*)d_in[0];  // [M,K]
  const float* w = (const float*)d_in[1];  // [K,N]
  float* out = (float*)d_out;              // [M,N]

  unsigned* scales = (unsigned*)d_ws;                       // [0]=absmax_x [1]=absmax_w
  unsigned char* xq = (unsigned char*)d_ws + 256;           // [M,K] fp8 (64 MiB)
  unsigned char* wq = xq + (size_t)M * K;                   // [N,K] fp8 (16 MiB)

  init_scales_kernel<<<1, 1, 0, stream>>>(scales);
  absmax_kernel<<<8192, 256, 0, stream>>>((const float4*)x, scales + 0, M * K / 4);
  absmax_kernel<<<2048, 256, 0, stream>>>((const float4*)w, scales + 1, K * N / 4);
  quant_x_kernel<<<(M * (long long)K / 16 + 255) / 256, 256, 0, stream>>>(
      x, xq, scales, (long long)M * K / 16);
  quant_wt_kernel<<<dim3(N / 64, K / 64), 256, 0, stream>>>(w, wq, scales, K, N);
  gemm_fp8_kernel<<<dim3(N / 128, M / 128), 256, 0, stream>>>(xq, wq, out,
                                                              scales, M, N, K);
}

// Round 2
// 923.205 us; speedup vs baseline: 1.0859x; 1.0859x over previous
//
#include <hip/hip_runtime.h>

#define FP8_MAX 448.0f

typedef float f32x16 __attribute__((ext_vector_type(16)));
typedef int v8i __attribute__((ext_vector_type(8)));
typedef int v4i __attribute__((ext_vector_type(4)));

// ---- async global->LDS, 16B per lane (m97) ----
__device__ __forceinline__ void load_lds16(const void* g, void* l) {
  __builtin_amdgcn_global_load_lds(
      (__attribute__((address_space(1))) void*)g,
      (__attribute__((address_space(3))) void*)l,
      16, 0, 0);
}

// ---- zero the two absmax slots (d_ws is poisoned 0xAA each call) ----
__global__ void init_scales_kernel(unsigned* s) {
  s[0] = 0u;
  s[1] = 0u;
}

// ---- per-tensor absmax: float4 grid-stride + wave64 reduce + atomicMax ----
__global__ void absmax_kernel(const float4* __restrict__ in,
                              unsigned* __restrict__ out, int n4) {
  float m = 0.f;
  int stride = gridDim.x * blockDim.x;
  for (int i = blockIdx.x * blockDim.x + threadIdx.x; i < n4; i += stride) {
    float4 v = in[i];
    m = fmaxf(m, fmaxf(fmaxf(fabsf(v.x), fabsf(v.y)),
                       fmaxf(fabsf(v.z), fabsf(v.w))));
  }
#pragma unroll
  for (int off = 32; off > 0; off >>= 1)
    m = fmaxf(m, __shfl_down(m, off, 64));
  __shared__ float sred[4];
  int lane = threadIdx.x & 63;
  int wid = threadIdx.x >> 6;
  if (lane == 0) sred[wid] = m;
  __syncthreads();
  if (threadIdx.x == 0) {
    m = fmaxf(fmaxf(sred[0], sred[1]), fmaxf(sred[2], sred[3]));
    atomicMax(out, __float_as_uint(m));  // positive floats: uint order == float order
  }
}

// ---- quantize fp32 -> fp8 e4m3, 4 elems/thread: float4 in, dword out ----
// (round 1 version did 64B/lane stride -> 64 cache lines per instruction;
//  this is fully coalesced on both sides)
__global__ void quant_x_kernel(const float4* __restrict__ x,
                               unsigned* __restrict__ xq,
                               const unsigned* __restrict__ sc, int n4) {
  int t = blockIdx.x * blockDim.x + threadIdx.x;
  if (t >= n4) return;
  float s = FP8_MAX / __uint_as_float(sc[0]);
  float4 v = x[t];
  float q0 = fminf(fmaxf(v.x * s, -FP8_MAX), FP8_MAX);
  float q1 = fminf(fmaxf(v.y * s, -FP8_MAX), FP8_MAX);
  float q2 = fminf(fmaxf(v.z * s, -FP8_MAX), FP8_MAX);
  float q3 = fminf(fmaxf(v.w * s, -FP8_MAX), FP8_MAX);
  int p = __builtin_amdgcn_cvt_pk_fp8_f32(q0, q1, 0, false);
  p = __builtin_amdgcn_cvt_pk_fp8_f32(q2, q3, p, true);
  xq[t] = (unsigned)p;
}

// ---- transpose+quantize w [K,N] fp32 -> wq_t [N,K] fp8, 64x64 LDS tiles ----
__global__ void quant_wt_kernel(const float* __restrict__ w,
                                unsigned char* __restrict__ wq,
                                const unsigned* __restrict__ sc, int K, int N) {
  __shared__ float tile[64][65];  // +1 pad: transposed reads land 2-way max
  float s = FP8_MAX / __uint_as_float(sc[1]);
  int nt = blockIdx.x * 64;
  int kt = blockIdx.y * 64;
#pragma unroll
  for (int it = 0; it < 4; ++it) {
    int idx = threadIdx.x + it * 256;
    int r = idx >> 4;        // k row within tile
    int c = (idx & 15) * 4;  // n col within tile
    float4 v = *(const float4*)&w[(size_t)(kt + r) * N + nt + c];
    tile[r][c + 0] = v.x; tile[r][c + 1] = v.y;
    tile[r][c + 2] = v.z; tile[r][c + 3] = v.w;
  }
  __syncthreads();
  int n = threadIdx.x >> 2;          // 0..63
  int k0 = (threadIdx.x & 3) * 16;   // 0,16,32,48
  unsigned r4[4];
#pragma unroll
  for (int q = 0; q < 4; ++q) {
    float a0 = fminf(fmaxf(tile[k0 + q * 4 + 0][n] * s, -FP8_MAX), FP8_MAX);
    float a1 = fminf(fmaxf(tile[k0 + q * 4 + 1][n] * s, -FP8_MAX), FP8_MAX);
    float a2 = fminf(fmaxf(tile[k0 + q * 4 + 2][n] * s, -FP8_MAX), FP8_MAX);
    float a3 = fminf(fmaxf(tile[k0 + q * 4 + 3][n] * s, -FP8_MAX), FP8_MAX);
    int p = __builtin_amdgcn_cvt_pk_fp8_f32(a0, a1, 0, false);
    p = __builtin_amdgcn_cvt_pk_fp8_f32(a2, a3, p, true);
    r4[q] = (unsigned)p;
  }
  uint4 o;
  o.x = r4[0]; o.y = r4[1]; o.z = r4[2]; o.w = r4[3];
  *(uint4*)&wq[(size_t)(nt + n) * K + kt + k0] = o;
}

// ---- MX-scaled fp8 GEMM: C[M,N] = Aq[M,K] . Bq[N,K]^T ----
// m148 recipe: 128x128 tile, BK=64B, 4 waves each 64x64 as 2x2 of 32x32,
// mfma_scale_f32_32x32x64_f8f6f4 (fmt=e4m3, scales=0x7F -> x1.0, i.e.
// numerically identical to non-scaled fp8 but 2x the MFMA rate).
// A-frag: lane holds row (lane&31), k-bytes (lane>>5)*32..+31 -> 2x b128.
// LDS chunk swizzle f(row)=row&3 so each row's fragment read covers all
// 16 banks of its half (row parity picks banks 0-15 vs 16-31).
__global__ __launch_bounds__(256) void gemm_fp8_kernel(
    const unsigned char* __restrict__ A,   // [M,K] fp8
    const unsigned char* __restrict__ B,   // [N,K] fp8
    float* __restrict__ C,                 // [M,N] fp32
    const unsigned* __restrict__ am, int M, int N, int K) {
  __shared__ unsigned char lA[128 * 64];
  __shared__ unsigned char lB[128 * 64];

  const int tid = threadIdx.x;
  const int lane = tid & 63;
  const int wave = tid >> 6;
  const int wm = (wave >> 1) * 64;
  const int wn = (wave & 1) * 64;
  const int l31 = lane & 31;
  const int kh = lane >> 5;  // which 32B k-half this lane holds

  const int m0 = blockIdx.y * 128;
  const int n0 = blockIdx.x * 128;

  f32x16 acc[2][2];
#pragma unroll
  for (int i = 0; i < 2; ++i)
#pragma unroll
    for (int j = 0; j < 2; ++j)
#pragma unroll
      for (int r = 0; r < 16; ++r) acc[i][j][r] = 0.f;

  // staging: thread stages LDS 16B chunk (tid&3) of row (tid>>2) (+64)
  // from global chunk (tid&3) ^ (row&3). row+64 has same (row&3).
  const int row0 = tid >> 2;
  const int sc0 = (tid & 3) ^ (row0 & 3);
  const int row1 = row0 + 64;
  const unsigned char* gA0 = A + (size_t)(m0 + row0) * K + sc0 * 16;
  const unsigned char* gA1 = A + (size_t)(m0 + row1) * K + sc0 * 16;
  const unsigned char* gB0 = B + (size_t)(n0 + row0) * K + sc0 * 16;
  const unsigned char* gB1 = B + (size_t)(n0 + row1) * K + sc0 * 16;
  unsigned char* sA0 = &lA[tid * 16];
  unsigned char* sA1 = &lA[(tid + 256) * 16];
  unsigned char* sB0 = &lB[tid * 16];
  unsigned char* sB1 = &lB[(tid + 256) * 16];

  // fragment read offsets (loop-invariant): [sub-tile][16B half]
  int aoff[2][2], boff[2][2];
#pragma unroll
  for (int sub = 0; sub < 2; ++sub) {
    int ra = wm + sub * 32 + l31;
    int fa = ra & 3;
    aoff[sub][0] = ra * 64 + ((kh * 2 + 0) ^ fa) * 16;
    aoff[sub][1] = ra * 64 + ((kh * 2 + 1) ^ fa) * 16;
    int rb = wn + sub * 32 + l31;
    int fb = rb & 3;
    boff[sub][0] = rb * 64 + ((kh * 2 + 0) ^ fb) * 16;
    boff[sub][1] = rb * 64 + ((kh * 2 + 1) ^ fb) * 16;
  }

  for (int k0 = 0; k0 < K; k0 += 64) {
    load_lds16(gA0 + k0, sA0);
    load_lds16(gA1 + k0, sA1);
    load_lds16(gB0 + k0, sB0);
    load_lds16(gB1 + k0, sB1);
    __syncthreads();  // drains vmcnt -> tiles resident

    v8i af[2], bf[2];
#pragma unroll
    for (int sub = 0; sub < 2; ++sub) {
      v4i alo = *(const v4i*)&lA[aoff[sub][0]];
      v4i ahi = *(const v4i*)&lA[aoff[sub][1]];
      af[sub] = __builtin_shufflevector(alo, ahi, 0, 1, 2, 3, 4, 5, 6, 7);
      v4i blo = *(const v4i*)&lB[boff[sub][0]];
      v4i bhi = *(const v4i*)&lB[boff[sub][1]];
      bf[sub] = __builtin_shufflevector(blo, bhi, 0, 1, 2, 3, 4, 5, 6, 7);
    }
#pragma unroll
    for (int si = 0; si < 2; ++si)
#pragma unroll
      for (int sj = 0; sj < 2; ++sj)
        acc[si][sj] = __builtin_amdgcn_mfma_scale_f32_32x32x64_f8f6f4(
            af[si], bf[sj], acc[si][sj],
            /*cbsz (fmt A)=*/0, /*blgp (fmt B)=*/0,
            /*opsel_a=*/0, /*scale_a=*/0x7f7f7f7f,
            /*opsel_b=*/0, /*scale_b=*/0x7f7f7f7f);

    __syncthreads();  // compute done before next staging overwrites LDS
  }

  // dequant: y / (sx*sw), sx=448/ax, sw=448/aw (match reference expressions)
  float ax = __uint_as_float(am[0]);
  float aw = __uint_as_float(am[1]);
  float sx = FP8_MAX / ax;
  float sw = FP8_MAX / aw;
  float inv = 1.f / (sx * sw);

  // 32x32 C/D layout (shape-determined, m74/m101/m121-128):
  // col = lane&31, row = (reg&3) + 8*(reg>>2) + 4*(lane>>5)
#pragma unroll
  for (int si = 0; si < 2; ++si)
#pragma unroll
    for (int sj = 0; sj < 2; ++sj) {
      int colbase = n0 + wn + sj * 32 + l31;
#pragma unroll
      for (int r = 0; r < 16; ++r) {
        int row = m0 + wm + si * 32 + (r & 3) + 8 * (r >> 2) + 4 * kh;
        C[(size_t)row * N + colbase] = acc[si][sj][r] * inv;
      }
    }
}

extern "C" void kernel_launch(void* const* d_in, const int* in_sizes, int n_in,
                              void* d_out, int out_size, void* d_ws,
                              size_t ws_size, hipStream_t stream) {
  const int M = 16384, K = 4096, N = 4096;
  const float* x = (const float*)d_in[0];  // [M,K]
  const float* w = (const float*)d_in[1];  // [K,N]
  float* out = (float*)d_out;              // [M,N]

  unsigned* scales = (unsigned*)d_ws;                 // [0]=absmax_x [1]=absmax_w
  unsigned char* xq = (unsigned char*)d_ws + 256;     // [M,K] fp8 (64 MiB)
  unsigned char* wq = xq + (size_t)M * K;             // [N,K] fp8 (16 MiB)

  init_scales_kernel<<<1, 1, 0, stream>>>(scales);
  absmax_kernel<<<8192, 256, 0, stream>>>((const float4*)x, scales + 0,
                                          M * K / 4);
  absmax_kernel<<<2048, 256, 0, stream>>>((const float4*)w, scales + 1,
                                          K * N / 4);
  quant_x_kernel<<<(M * K / 4 + 255) / 256, 256, 0, stream>>>(
      (const float4*)x, (unsigned*)xq, scales, M * K / 4);
  quant_wt_kernel<<<dim3(N / 64, K / 64), 256, 0, stream>>>(w, wq, scales, K,
                                                            N);
  gemm_fp8_kernel<<<dim3(N / 128, M / 128), 256, 0, stream>>>(xq, wq, out,
                                                              scales, M, N, K);
}